// Round 3
// baseline (264.473 us; speedup 1.0000x reference)
//
#include <hip/hip_runtime.h>
#include <stdint.h>

typedef unsigned short u16;
typedef __bf16 bf16x8 __attribute__((ext_vector_type(8)));
typedef float f32x4 __attribute__((ext_vector_type(4)));

__device__ __forceinline__ u16 f2bf(float f) {
  union { float f; uint32_t u; } x; x.f = f;
  uint32_t u = x.u;
  u += 0x7fffu + ((u >> 16) & 1u);   // round-to-nearest-even
  return (u16)(u >> 16);
}
__device__ __forceinline__ float bf2f(uint32_t lo16) {
  union { uint32_t u; float f; } x; x.u = lo16 << 16; return x.f;
}

__device__ __forceinline__ void async_load16(const u16* g, u16* l) {
  __builtin_amdgcn_global_load_lds(
      (const __attribute__((address_space(1))) void*)g,
      (__attribute__((address_space(3))) void*)l,
      16, 0, 0);
}

// ---------------- prep_all: sigmoid(beta) + weight converts + x convert ----------------
__global__ __launch_bounds__(256) void prep_all(const float* __restrict__ x,
                                                const float* __restrict__ Wq,
                                                const float* __restrict__ Wfc,
                                                const float* __restrict__ braw,
                                                u16* __restrict__ xb,
                                                u16* __restrict__ wqb,
                                                u16* __restrict__ wfcb,
                                                float* __restrict__ beta) {
  int gid = blockIdx.x * 256 + threadIdx.x;
  if (gid < 1024) beta[gid] = 1.0f / (1.0f + expf(-braw[gid]));
  if (gid < 131072) {
    const int HH = 1024 * 1024;
    int i = gid * 16;
    const float* src = (i < HH) ? (Wq + i) : (Wfc + (i - HH));
    u16* dst = (i < HH) ? (wqb + i) : (wfcb + (i - HH));
#pragma unroll
    for (int c = 0; c < 4; c++) {
      float4 v = *(const float4*)(src + c * 4);
      ushort4 o = {f2bf(v.x), f2bf(v.y), f2bf(v.z), f2bf(v.w)};
      *(ushort4*)(dst + c * 4) = o;
    }
  }
  {
    int i = gid * 8;
    float4 a = *(const float4*)(x + i);
    float4 b = *(const float4*)(x + i + 4);
    ushort4 o0 = {f2bf(a.x), f2bf(a.y), f2bf(a.z), f2bf(a.w)};
    ushort4 o1 = {f2bf(b.x), f2bf(b.y), f2bf(b.z), f2bf(b.w)};
    *(ushort4*)(xb + i) = o0;
    *(ushort4*)(xb + i + 4) = o1;
  }
}

// ---------------- GEMM: C = A (MxK bf16) * B^T (NxK bf16) + bias ----------------
// 256x256 tile, BK=64, 8 waves (2Mx4N), per-wave 128x64.
//
// R3 redesign (post-mortem of R2): the binding resource was LDS read BW --
// 192 KB of ds_read_b128 per CU per K-tile (~1500-2300 cyc) vs the 2483-cyc
// MFMA floor, phase-serialized by barriers. Fix: B (weights, 2 MB, L2/LLC
// resident) is loaded GLOBAL -> REGISTER directly (fragment pattern = 16
// rows x 64 B contiguous per instr = 16 fully-consumed cache lines), double
// buffered in regs. Only A goes through LDS (DMA, double-buffered 2x32 KB).
//   * LDS read traffic: 192 -> 128 KB/K-tile (under the MFMA floor).
//   * ONE barrier per K-tile; counted s_waitcnt vmcnt(8) (A-DMA issued
//     FIRST, then 8 B plain loads, sched_barrier(0) fences pin the issue
//     order so the count is sound; vmcnt(8) leaves exactly the 8 B loads
//     in flight and guarantees the 4 A-DMA issues landed). B-register
//     dependencies are compiler-tracked (plain loads).
//   * Compute body (16 ds_read + 32 MFMA) is left to the compiler to
//     software-pipeline with fine-grained lgkmcnt (m97-proven mode) -- no
//     mid-tile barriers or drains.
//   * lgkmcnt(0) + sched_barrier(0) before the tile barrier: guarantees all
//     ds_reads of tile t are complete before any wave crosses the barrier
//     and issues the A(t+2) DMA into the buffer tile t was reading
//     (rule-18 pattern: "memory" clobber alone does not order reg-only
//     MFMA/ds consumers).
// Loop unrolled x2 so A-buffer and B-register-set swaps are static (rule 20).
template <int RELU, int OUTBF>
__global__ __launch_bounds__(512, 2) void gemm256(const u16* __restrict__ A,
                                                  const u16* __restrict__ B,
                                                  const float* __restrict__ bias,
                                                  void* __restrict__ Cout,
                                                  int M, int N, int K) {
  __shared__ u16 lds[2][256 * 64];  // A double-buffer, 64 KiB

  const int tid  = threadIdx.x;
  const int lane = tid & 63;
  const int wid  = tid >> 6;          // 0..7
  const int wr   = (wid >> 2) * 128;  // wave row offset in tile
  const int wc   = (wid & 3) * 64;    // wave col offset in tile

  // XCD-aware map (kept from R2: FETCH 67.6 -> 24.6 MB): grid 256 = 64
  // m-tiles x 4 n-tiles; xcd = bid&7 owns m-tiles [8c,8c+8) x all n.
  const int bid    = blockIdx.x;
  const int xcd    = bid & 7;
  const int idx    = bid >> 3;
  const int tile_m = ((xcd << 3) | (idx >> 2)) * 256;
  const int tile_n = (idx & 3) * 256;

  // A staging map: one issue = 512 thr x 16B = 64 rows x 128B; dest linear,
  // source chunk pre-swizzled (global_load_lds dest must be wave-uniform
  // base + lane*16). LDS[r][c] holds global chunk c ^ (r&7).
  const int srow = tid >> 3;                  // 0..63
  const int sch  = (tid & 7) ^ (srow & 7);
  const u16* gA = A + (size_t)(tile_m + srow) * K + sch * 8;

#define STAGE_A(bp, kt)                                                \
  do {                                                                 \
    const u16* _s = gA + (size_t)(kt) * 64;                            \
    async_load16(_s,                   &(bp)[wid * 512]);              \
    async_load16(_s + (size_t)64 * K,  &(bp)[4096 + wid * 512]);       \
    async_load16(_s + (size_t)128 * K, &(bp)[8192 + wid * 512]);       \
    async_load16(_s + (size_t)192 * K, &(bp)[12288 + wid * 512]);      \
  } while (0)

  f32x4 acc[8][4];
#pragma unroll
  for (int i = 0; i < 8; i++)
#pragma unroll
    for (int j = 0; j < 4; j++) acc[i][j] = (f32x4){0.f, 0.f, 0.f, 0.f};

  const int lrow = lane & 15;
  const int kq   = lane >> 4;
  const int x0   = ((kq)     ^ (lrow & 7)) << 3;  // A ksub-0 chunk offset
  const int x1   = ((kq + 4) ^ (lrow & 7)) << 3;  // A ksub-1

  // B fragment base: lanes cover 16 rows (lrow) x 4 k-chunks (kq) = 16 full
  // 64B lines per load instruction.
  const u16* gBf = B + (size_t)(tile_n + wc + lrow) * K + kq * 8;

  const int NT = K >> 6;  // K-tiles of 64 (K=1024 -> 16, even)

  bf16x8 bA[4][2], bB[4][2];

  // ---- prologue: A(0) DMA first, then B(0) -> regs; vmcnt(8) drains A ----
  STAGE_A(lds[0], 0);
  __builtin_amdgcn_sched_barrier(0);
#pragma unroll
  for (int n = 0; n < 4; n++) {
    bA[n][0] = *(const bf16x8*)(gBf + (size_t)n * 16 * K);
    bA[n][1] = *(const bf16x8*)(gBf + (size_t)n * 16 * K + 32);
  }
  __builtin_amdgcn_sched_barrier(0);
  asm volatile("s_waitcnt vmcnt(8)" ::: "memory");
  __builtin_amdgcn_s_barrier();

  auto iter = [&](int t, u16* __restrict__ Ac, u16* __restrict__ An,
                  bf16x8 (&bc)[4][2], bf16x8 (&bn)[4][2]) {
    const int t1 = t + 1;
    if (t1 < NT) STAGE_A(An, t1);          // 4 DMA (oldest in this tile)
    __builtin_amdgcn_sched_barrier(0);
    if (t1 < NT) {
#pragma unroll
      for (int n = 0; n < 4; n++) {        // 8 plain loads (newest)
        bn[n][0] = *(const bf16x8*)(gBf + (size_t)n * 16 * K + (size_t)t1 * 64);
        bn[n][1] = *(const bf16x8*)(gBf + (size_t)n * 16 * K + (size_t)t1 * 64 + 32);
      }
    }
    __builtin_amdgcn_sched_barrier(0);
    // compute: compiler-scheduled ds_read <-> MFMA interleave (fine lgkmcnt)
#pragma unroll
    for (int i = 0; i < 8; i++) {
      bf16x8 a0 = *(const bf16x8*)&Ac[(wr + i * 16 + lrow) * 64 + x0];
      bf16x8 a1 = *(const bf16x8*)&Ac[(wr + i * 16 + lrow) * 64 + x1];
#pragma unroll
      for (int n = 0; n < 4; n++) {
        acc[i][n] = __builtin_amdgcn_mfma_f32_16x16x32_bf16(a0, bc[n][0], acc[i][n], 0, 0, 0);
        acc[i][n] = __builtin_amdgcn_mfma_f32_16x16x32_bf16(a1, bc[n][1], acc[i][n], 0, 0, 0);
      }
    }
    if (t1 < NT) {
      asm volatile("s_waitcnt lgkmcnt(0)" ::: "memory");   // tile-t ds_reads done
      __builtin_amdgcn_sched_barrier(0);                   // rule 18 fence
      asm volatile("s_waitcnt vmcnt(8)" ::: "memory");     // A(t+1) landed; B(t+1) may fly
      __builtin_amdgcn_s_barrier();
    }
  };

  for (int t = 0; t < NT; t += 2) {
    iter(t, lds[0], lds[1], bA, bB);
    if (t + 1 < NT) iter(t + 1, lds[1], lds[0], bB, bA);
  }
#undef STAGE_A

  // C/D layout: col = lane&15, row = (lane>>4)*4 + r  [measured m89/m91]
  const int crow = (lane >> 4) << 2;
  const int ccol = lane & 15;
#pragma unroll
  for (int i = 0; i < 8; i++) {
#pragma unroll
    for (int j = 0; j < 4; j++) {
      const int gm = tile_m + wr + i * 16 + crow;
      const int gn = tile_n + wc + j * 16 + ccol;
      const float bv = bias[gn];
#pragma unroll
      for (int r = 0; r < 4; r++) {
        float v = acc[i][j][r] + bv;
        if (RELU) v = fmaxf(v, 0.f);
        if (OUTBF) ((u16*)Cout)[(size_t)(gm + r) * N + gn] = f2bf(v);
        else       ((float*)Cout)[(size_t)(gm + r) * N + gn] = v;
      }
    }
  }
}

// ---------------- scan: m_t = beta*m_{t-1} + q_t over T=2048, channels = B*H = 8192 ----
// q is bf16 [T][8192]. 64 segments of 32 t-steps.
#define NCH 8192
#define SEG 32
#define NSEG 64

// pass1: per-segment carries (fp32 Horner over bf16 q; no double quantization).
__global__ __launch_bounds__(256) void scan_carry(const uint2* __restrict__ qb,
                                                  float* __restrict__ carry,
                                                  const float* __restrict__ beta_arr) {
  int tid = blockIdx.x * 256 + threadIdx.x;  // [0, 64*2048)
  int seg = tid >> 11;
  int cq  = tid & 2047;                      // channel quad
  int h0  = (cq * 4) & 1023;
  float b0 = beta_arr[h0], b1 = beta_arr[h0 + 1], b2 = beta_arr[h0 + 2], b3 = beta_arr[h0 + 3];
  const uint2* p = qb + (size_t)seg * SEG * 2048 + cq;
  float m0 = 0.f, m1 = 0.f, m2 = 0.f, m3 = 0.f;
#pragma unroll 8
  for (int t = 0; t < SEG; t++) {
    uint2 v = p[(size_t)t * 2048];
    m0 = fmaf(b0, m0, bf2f(v.x & 0xffffu));
    m1 = fmaf(b1, m1, bf2f(v.x >> 16));
    m2 = fmaf(b2, m2, bf2f(v.y & 0xffffu));
    m3 = fmaf(b3, m3, bf2f(v.y >> 16));
  }
  *(float4*)&carry[(size_t)seg * NCH + cq * 4] = make_float4(m0, m1, m2, m3);
}

// pass2 (fused fold + rescan): F = Horner-fold of the seg upstream carries with
// ratio beta^32 (2 MB buffer, L2-resident), then rescan 32 q steps from m=F and
// emit bf16 m. seg is uniform per block (8 blocks per segment).
__global__ __launch_bounds__(256) void scan_fuse(const uint2* __restrict__ qb,
                                                 const float4* __restrict__ carry4,
                                                 const float* __restrict__ beta_arr,
                                                 uint2* __restrict__ mb) {
  const int tid = blockIdx.x * 256 + threadIdx.x;  // [0, 64*2048)
  const int seg = tid >> 11;
  const int cq  = tid & 2047;
  const int h0  = (cq * 4) & 1023;
  const float b0 = beta_arr[h0], b1 = beta_arr[h0 + 1];
  const float b2 = beta_arr[h0 + 2], b3 = beta_arr[h0 + 3];
  float s0 = b0, s1 = b1, s2 = b2, s3 = b3;
#pragma unroll
  for (int i = 0; i < 5; i++) { s0 *= s0; s1 *= s1; s2 *= s2; s3 *= s3; }  // beta^32
  float m0 = 0.f, m1 = 0.f, m2 = 0.f, m3 = 0.f;
  const float4* cp = carry4 + cq;
  for (int s = 0; s < seg; s++) {  // uniform per block
    float4 c = cp[(size_t)s * 2048];
    m0 = fmaf(s0, m0, c.x); m1 = fmaf(s1, m1, c.y);
    m2 = fmaf(s2, m2, c.z); m3 = fmaf(s3, m3, c.w);
  }
  const uint2* p = qb + (size_t)seg * SEG * 2048 + cq;
  uint2* o = mb + (size_t)seg * SEG * 2048 + cq;
#pragma unroll 8
  for (int t = 0; t < SEG; t++) {
    uint2 v = p[(size_t)t * 2048];
    m0 = fmaf(b0, m0, bf2f(v.x & 0xffffu));
    m1 = fmaf(b1, m1, bf2f(v.x >> 16));
    m2 = fmaf(b2, m2, bf2f(v.y & 0xffffu));
    m3 = fmaf(b3, m3, bf2f(v.y >> 16));
    uint2 w;
    w.x = (uint32_t)f2bf(m0) | ((uint32_t)f2bf(m1) << 16);
    w.y = (uint32_t)f2bf(m2) | ((uint32_t)f2bf(m3) << 16);
    o[(size_t)t * 2048] = w;
  }
}

extern "C" void kernel_launch(void* const* d_in, const int* in_sizes, int n_in,
                              void* d_out, int out_size, void* d_ws, size_t ws_size,
                              hipStream_t stream) {
  const float* x        = (const float*)d_in[0];
  const float* W_q      = (const float*)d_in[1];
  const float* b_q      = (const float*)d_in[2];
  const float* beta_raw = (const float*)d_in[3];
  const float* W_fc     = (const float*)d_in[4];
  const float* b_fc     = (const float*)d_in[5];

  const int H = 1024;
  const int M = 2048 * 8;              // T*B = 16384 rows
  const size_t MH = (size_t)M * H;     // 16.7M elements

  char* ws = (char*)d_ws;
  u16* x_bf    = (u16*)ws;  ws += MH * 2;                   // 32 MB
  u16* q_bf    = (u16*)ws;  ws += MH * 2;                   // 32 MB
  u16* m_bf    = (u16*)ws;  ws += MH * 2;                   // 32 MB
  u16* wq_bf   = (u16*)ws;  ws += (size_t)H * H * 2;        // 2 MB
  u16* wfc_bf  = (u16*)ws;  ws += (size_t)H * H * 2;        // 2 MB
  float* beta  = (float*)ws; ws += 4096;
  float* carry = (float*)ws; ws += (size_t)NSEG * NCH * 4;  // 2 MB

  prep_all<<<(int)(MH / 8 / 256), 256, 0, stream>>>(x, W_q, W_fc, beta_raw,
                                                    x_bf, wq_bf, wfc_bf, beta);

  gemm256<0, 1><<<256, 512, 0, stream>>>(x_bf, wq_bf, b_q, q_bf, M, H, H);

  scan_carry<<<NSEG * (NCH / 4) / 256, 256, 0, stream>>>((const uint2*)q_bf, carry, beta);
  scan_fuse<<<NSEG * (NCH / 4) / 256, 256, 0, stream>>>((const uint2*)q_bf,
                                                        (const float4*)carry, beta,
                                                        (uint2*)m_bf);

  gemm256<1, 0><<<256, 512, 0, stream>>>(m_bf, wfc_bf, b_fc, d_out, M, H, H);
}

// Round 4
// 234.890 us; speedup vs baseline: 1.1259x; 1.1259x over previous
//
#include <hip/hip_runtime.h>
#include <stdint.h>

typedef unsigned short u16;
typedef __bf16 bf16x8 __attribute__((ext_vector_type(8)));
typedef float f32x4 __attribute__((ext_vector_type(4)));

__device__ __forceinline__ u16 f2bf(float f) {
  union { float f; uint32_t u; } x; x.f = f;
  uint32_t u = x.u;
  u += 0x7fffu + ((u >> 16) & 1u);   // round-to-nearest-even
  return (u16)(u >> 16);
}
__device__ __forceinline__ float bf2f(uint32_t lo16) {
  union { uint32_t u; float f; } x; x.u = lo16 << 16; return x.f;
}

__device__ __forceinline__ void async_load16(const u16* g, u16* l) {
  __builtin_amdgcn_global_load_lds(
      (const __attribute__((address_space(1))) void*)g,
      (__attribute__((address_space(3))) void*)l,
      16, 0, 0);
}

// ---------------- prep_all: sigmoid(beta) + weight converts + x convert ----------------
__global__ __launch_bounds__(256) void prep_all(const float* __restrict__ x,
                                                const float* __restrict__ Wq,
                                                const float* __restrict__ Wfc,
                                                const float* __restrict__ braw,
                                                u16* __restrict__ xb,
                                                u16* __restrict__ wqb,
                                                u16* __restrict__ wfcb,
                                                float* __restrict__ beta) {
  int gid = blockIdx.x * 256 + threadIdx.x;
  if (gid < 1024) beta[gid] = 1.0f / (1.0f + expf(-braw[gid]));
  if (gid < 131072) {
    const int HH = 1024 * 1024;
    int i = gid * 16;
    const float* src = (i < HH) ? (Wq + i) : (Wfc + (i - HH));
    u16* dst = (i < HH) ? (wqb + i) : (wfcb + (i - HH));
#pragma unroll
    for (int c = 0; c < 4; c++) {
      float4 v = *(const float4*)(src + c * 4);
      ushort4 o = {f2bf(v.x), f2bf(v.y), f2bf(v.z), f2bf(v.w)};
      *(ushort4*)(dst + c * 4) = o;
    }
  }
  {
    int i = gid * 8;
    float4 a = *(const float4*)(x + i);
    float4 b = *(const float4*)(x + i + 4);
    ushort4 o0 = {f2bf(a.x), f2bf(a.y), f2bf(a.z), f2bf(a.w)};
    ushort4 o1 = {f2bf(b.x), f2bf(b.y), f2bf(b.z), f2bf(b.w)};
    *(ushort4*)(xb + i) = o0;
    *(ushort4*)(xb + i + 4) = o1;
  }
}

// ---------------- GEMM: C = A (MxK bf16) * B^T (NxK bf16) + bias ----------------
// R4 = R1's harness-verified ring schedule (best measured: 46.4 us, monolithic
// MFMA body, counted vmcnt, BK=32, 4-deep LDS ring) + R2's proven XCD swizzle
// (FETCH 67.6 -> 24.6 MB) + fused scan-carry epilogue (CARRY=1, GEMM1 only).
//
// Ring (from R1, measured): 256x256 tile, BK=32, 8 waves (2Mx4N), per-wave
// 128x64 via 8x4 mfma_f32_16x16x32_bf16. 4-deep K-tile ring; stage kt+3 while
// computing kt; end-of-iter wait is counted vmcnt(8) (2 future tiles x 4
// issues in flight), never 0 until the tail. Race-freedom: slot (kt+3)&3 was
// last ds_read at iteration kt-1, whose reads complete before its end
// barrier (compiler lgkmcnt before MFMA).
//
// CARRY epilogue (GEMM1): block's 256 output rows = one scan segment
// (32 t x 8 b), so carry[seg] = sum_t beta^(31-t) (acc+bias) is computable
// in-register. Lane algebra: row8 = wr + 16i + 4*c4 + r (c4 = lane>>4)
// -> t_local = 2i + kappa + 16W (kappa = lane>>5, W = wr>>7), b = (4*c4+r)&7.
// Per (j,r): Horner in beta^2 ascending i, scale by beta^(17-kappa-16W);
// kappa-halves combine via shfl_xor(32) (same b,h, opposite t parity);
// W-halves combine via 16 KB LDS ps[2][8][256] (aliased into ring slot 0:
// last read at kt = NKT-4, >= 2 barriers before epilogue -> race-free) +
// one __syncthreads. fp32-q carry is MORE accurate than the old bf16-q pass.
template <int RELU, int OUTBF, int CARRY>
__global__ __launch_bounds__(512, 2) void gemm256(const u16* __restrict__ A,
                                                  const u16* __restrict__ B,
                                                  const float* __restrict__ bias,
                                                  void* __restrict__ Cout,
                                                  const float* __restrict__ beta_arr,
                                                  float* __restrict__ carry_out,
                                                  int M, int N, int K) {
  // ring[slot][matrix][256 rows][32 cols bf16] ; 4*2*16KB = 128 KiB
  __shared__ u16 lds[4][2][256 * 32];

  const int tid  = threadIdx.x;
  const int lane = tid & 63;
  const int wid  = tid >> 6;          // 0..7
  const int wr   = (wid >> 2) * 128;  // wave row offset within tile
  const int wc   = (wid & 3) * 64;    // wave col offset within tile

  // XCD-aware map (proven in R2): grid 256 = 64 m-tiles x 4 n-tiles;
  // xcd = bid&7 owns m-tiles [8c,8c+8) x all n -> the 4 blocks sharing an
  // A-panel are concurrent on one XCD's L2. 256 % 8 == 0 -> bijective.
  const int bid    = blockIdx.x;
  const int xcd    = bid & 7;
  const int idx    = bid >> 3;
  const int tile_m = ((xcd << 3) | (idx >> 2)) * 256;
  const int tile_n = (idx & 3) * 256;

  // staging: per issue, 512 threads cover 128 rows x 4 chunks(16B). Thread:
  // row-in-issue = tid>>2, dest chunk = tid&3, src chunk pre-swizzled
  // (global_load_lds dest must be wave-uniform base + lane*16 -> linear).
  const int srow    = tid >> 2;                    // 0..127
  const int schunk  = (tid & 3) ^ ((srow >> 1) & 3);
  const u16* gA = A + (size_t)(tile_m + srow) * K + schunk * 8;
  const u16* gB = B + (size_t)(tile_n + srow) * K + schunk * 8;
  const size_t half_stride = (size_t)128 * K;      // rows 128..255 of the tile

#define STAGE(slot, kt)                                                   \
  do {                                                                    \
    const size_t k0 = (size_t)(kt) * 32;                                  \
    async_load16(gA + k0,               &lds[slot][0][wid * 512]);        \
    async_load16(gA + k0 + half_stride, &lds[slot][0][4096 + wid * 512]); \
    async_load16(gB + k0,               &lds[slot][1][wid * 512]);        \
    async_load16(gB + k0 + half_stride, &lds[slot][1][4096 + wid * 512]); \
  } while (0)

  f32x4 acc[8][4];
#pragma unroll
  for (int i = 0; i < 8; i++)
#pragma unroll
    for (int j = 0; j < 4; j++) acc[i][j] = (f32x4){0.f, 0.f, 0.f, 0.f};

  const int lrow = lane & 15;
  const int kq   = lane >> 4;
  const int kc   = (lrow >> 1) & 3;        // read-side swizzle key
  const int coff = ((kq ^ kc) << 3);       // elem offset within a 32-elem row

  const int NKT = K >> 5;                  // K-tiles of 32 (K=1024 -> 32)

  // prologue: fill 3 ring slots, then wait for slot 0 only (8 newer issues allowed)
  STAGE(0, 0);
  if (NKT > 1) STAGE(1, 1);
  if (NKT > 2) STAGE(2, 2);
  if (NKT > 2)      asm volatile("s_waitcnt vmcnt(8)" ::: "memory");
  else if (NKT > 1) asm volatile("s_waitcnt vmcnt(4)" ::: "memory");
  else              asm volatile("s_waitcnt vmcnt(0)" ::: "memory");
  __builtin_amdgcn_s_barrier();

  for (int kt = 0; kt < NKT; ++kt) {
    const int slot = kt & 3;
    const u16* As = &lds[slot][0][0];
    const u16* Bs = &lds[slot][1][0];

    bf16x8 a[8], b[4];
#pragma unroll
    for (int i = 0; i < 8; i++)
      a[i] = *(const bf16x8*)&As[(wr + i * 16 + lrow) * 32 + coff];
#pragma unroll
    for (int j = 0; j < 4; j++)
      b[j] = *(const bf16x8*)&Bs[(wc + j * 16 + lrow) * 32 + coff];

    if (kt + 3 < NKT) STAGE((kt + 3) & 3, kt + 3);

    __builtin_amdgcn_s_setprio(1);
#pragma unroll
    for (int i = 0; i < 8; i++)
#pragma unroll
      for (int j = 0; j < 4; j++)
        acc[i][j] = __builtin_amdgcn_mfma_f32_16x16x32_bf16(a[i], b[j], acc[i][j], 0, 0, 0);
    __builtin_amdgcn_s_setprio(0);

    // counted wait: guarantee kt+1's 4 issues landed; leave newer tiles in flight.
    const int ahead = NKT - 1 - kt;
    if (ahead >= 3) {
      asm volatile("s_waitcnt vmcnt(8)" ::: "memory");
      __builtin_amdgcn_s_barrier();
    } else if (ahead == 2) {
      asm volatile("s_waitcnt vmcnt(4)" ::: "memory");
      __builtin_amdgcn_s_barrier();
    } else if (ahead == 1) {
      asm volatile("s_waitcnt vmcnt(0)" ::: "memory");
      __builtin_amdgcn_s_barrier();
    }
  }
#undef STAGE

  // C/D layout: col = lane&15, row = (lane>>4)*4 + r  [measured m89/m91]
  const int crow = (lane >> 4) << 2;
  const int ccol = lane & 15;
#pragma unroll
  for (int i = 0; i < 8; i++) {
#pragma unroll
    for (int j = 0; j < 4; j++) {
      const int gm = tile_m + wr + i * 16 + crow;
      const int gn = tile_n + wc + j * 16 + ccol;
      const float bv = bias[gn];
#pragma unroll
      for (int r = 0; r < 4; r++) {
        float v = acc[i][j][r] + bv;
        if (RELU) v = fmaxf(v, 0.f);
        if (OUTBF) ((u16*)Cout)[(size_t)(gm + r) * N + gn] = f2bf(v);
        else       ((float*)Cout)[(size_t)(gm + r) * N + gn] = v;
      }
    }
  }

  if (CARRY) {
    // ---- fused scan_carry: carry[seg][b*1024+h] = sum_t beta_h^(31-t) q_t ----
    float* ps = (float*)&lds[0][0][0];   // [2][8][256] f32 = 16 KB (ring slot 0)
    const int W   = wr >> 7;             // t-half (0: t 0..15, 1: t 16..31)
    const int kap = lane >> 5;           // t parity offset
#pragma unroll
    for (int j = 0; j < 4; j++) {
      const int gn = tile_n + wc + j * 16 + ccol;
      const float bv = bias[gn];
      const float b1 = beta_arr[gn];
      const float b2 = b1 * b1;
      const float b4 = b2 * b2, b8 = b4 * b4, b16 = b8 * b8;
      // scale = beta^(17 - kap - 16W)
      const float scale = W ? (kap ? 1.0f : b1) : (kap ? b16 : b16 * b1);
#pragma unroll
      for (int r = 0; r < 4; r++) {
        // inner = sum_i beta^(14-2i) (acc[i]+bv)  (Horner ascending i)
        float Hn = acc[0][j][r] + bv;
#pragma unroll
        for (int i = 1; i < 8; i++) Hn = fmaf(b2, Hn, acc[i][j][r] + bv);
        float P = scale * Hn;
        P += __shfl_xor(P, 32);          // combine kappa halves (lane^32: same b,h)
        if (lane < 32) {
          const int bb = ((lane >> 4) << 2) + r;   // b index 0..7
          ps[W * 2048 + bb * 256 + wc + j * 16 + ccol] = P;
        }
      }
    }
    __syncthreads();
    {
      // combine t-halves and store 2048 carries (8 b x 256 h), float4/thread
      const int bb = tid >> 6;
      const int h4 = (tid & 63) << 2;
      float4 lo = *(float4*)&ps[bb * 256 + h4];
      float4 hi = *(float4*)&ps[2048 + bb * 256 + h4];
      float4 s  = make_float4(lo.x + hi.x, lo.y + hi.y, lo.z + hi.z, lo.w + hi.w);
      const int seg = tile_m >> 8;
      *(float4*)&carry_out[(size_t)seg * 8192 + bb * 1024 + tile_n + h4] = s;
    }
  }
}

// ---------------- scan: m_t = beta*m_{t-1} + q_t over T=2048, channels = B*H = 8192 ----
// q is bf16 [T][8192]. 64 segments of 32 t-steps. Per-segment carries now come
// from GEMM1's fused epilogue (fp32-q Horner).
#define NCH 8192
#define SEG 32
#define NSEG 64

// fused fold + rescan: F = Horner-fold of the seg upstream carries with
// ratio beta^32 (2 MB buffer, L2-resident), then rescan 32 q steps from m=F and
// emit bf16 m. seg is uniform per block (8 blocks per segment).
__global__ __launch_bounds__(256) void scan_fuse(const uint2* __restrict__ qb,
                                                 const float4* __restrict__ carry4,
                                                 const float* __restrict__ beta_arr,
                                                 uint2* __restrict__ mb) {
  const int tid = blockIdx.x * 256 + threadIdx.x;  // [0, 64*2048)
  const int seg = tid >> 11;
  const int cq  = tid & 2047;
  const int h0  = (cq * 4) & 1023;
  const float b0 = beta_arr[h0], b1 = beta_arr[h0 + 1];
  const float b2 = beta_arr[h0 + 2], b3 = beta_arr[h0 + 3];
  float s0 = b0, s1 = b1, s2 = b2, s3 = b3;
#pragma unroll
  for (int i = 0; i < 5; i++) { s0 *= s0; s1 *= s1; s2 *= s2; s3 *= s3; }  // beta^32
  float m0 = 0.f, m1 = 0.f, m2 = 0.f, m3 = 0.f;
  const float4* cp = carry4 + cq;
  for (int s = 0; s < seg; s++) {  // uniform per block
    float4 c = cp[(size_t)s * 2048];
    m0 = fmaf(s0, m0, c.x); m1 = fmaf(s1, m1, c.y);
    m2 = fmaf(s2, m2, c.z); m3 = fmaf(s3, m3, c.w);
  }
  const uint2* p = qb + (size_t)seg * SEG * 2048 + cq;
  uint2* o = mb + (size_t)seg * SEG * 2048 + cq;
#pragma unroll 8
  for (int t = 0; t < SEG; t++) {
    uint2 v = p[(size_t)t * 2048];
    m0 = fmaf(b0, m0, bf2f(v.x & 0xffffu));
    m1 = fmaf(b1, m1, bf2f(v.x >> 16));
    m2 = fmaf(b2, m2, bf2f(v.y & 0xffffu));
    m3 = fmaf(b3, m3, bf2f(v.y >> 16));
    uint2 w;
    w.x = (uint32_t)f2bf(m0) | ((uint32_t)f2bf(m1) << 16);
    w.y = (uint32_t)f2bf(m2) | ((uint32_t)f2bf(m3) << 16);
    o[(size_t)t * 2048] = w;
  }
}

extern "C" void kernel_launch(void* const* d_in, const int* in_sizes, int n_in,
                              void* d_out, int out_size, void* d_ws, size_t ws_size,
                              hipStream_t stream) {
  const float* x        = (const float*)d_in[0];
  const float* W_q      = (const float*)d_in[1];
  const float* b_q      = (const float*)d_in[2];
  const float* beta_raw = (const float*)d_in[3];
  const float* W_fc     = (const float*)d_in[4];
  const float* b_fc     = (const float*)d_in[5];

  const int H = 1024;
  const int M = 2048 * 8;              // T*B = 16384 rows
  const size_t MH = (size_t)M * H;     // 16.7M elements

  char* ws = (char*)d_ws;
  u16* x_bf    = (u16*)ws;  ws += MH * 2;                   // 32 MB
  u16* q_bf    = (u16*)ws;  ws += MH * 2;                   // 32 MB
  u16* m_bf    = (u16*)ws;  ws += MH * 2;                   // 32 MB
  u16* wq_bf   = (u16*)ws;  ws += (size_t)H * H * 2;        // 2 MB
  u16* wfc_bf  = (u16*)ws;  ws += (size_t)H * H * 2;        // 2 MB
  float* beta  = (float*)ws; ws += 4096;
  float* carry = (float*)ws; ws += (size_t)NSEG * NCH * 4;  // 2 MB

  prep_all<<<(int)(MH / 8 / 256), 256, 0, stream>>>(x, W_q, W_fc, beta_raw,
                                                    x_bf, wq_bf, wfc_bf, beta);

  // GEMM1 + fused segment-carry epilogue (replaces the scan_carry dispatch)
  gemm256<0, 1, 1><<<256, 512, 0, stream>>>(x_bf, wq_bf, b_q, q_bf,
                                            beta, carry, M, H, H);

  scan_fuse<<<NSEG * (NCH / 4) / 256, 256, 0, stream>>>((const uint2*)q_bf,
                                                        (const float4*)carry, beta,
                                                        (uint2*)m_bf);

  gemm256<1, 0, 0><<<256, 512, 0, stream>>>(m_bf, wfc_bf, b_fc, d_out,
                                            beta, nullptr, M, H, H);
}